// Round 11
// baseline (1841.737 us; speedup 1.0000x reference)
//
#include <hip/hip_runtime.h>

// EdgeConv: sorted edges + MFMA edge GEMM.
// h = relu([x_i || x_j - x_i] @ W1 + b1) = relu(A[row] + B[col])
//   A = x@(W1top - W1bot) + b1 (cols 0..511 of AB), B = x@W1bot (cols 512..1023)
// out[i] = sum_edges (h @ W2 + b2); edges counting-sorted by row.
// Edge GEMM (2-product): acc = bf16(h)@W2hi + bf16(h)@W2lo  (drops hl@W2 ~2^-9 rel).
// 64 edges x 256 cols per block, 4 waves, acc[4][4] -> ~124 total regs -> 4 waves/SIMD.

#define N_NODES 50000
#define N_EDGES 800000

typedef __attribute__((ext_vector_type(8))) short  bf16x8;
typedef __attribute__((ext_vector_type(8))) unsigned short ushort8;
typedef __attribute__((ext_vector_type(4))) float  f32x4;

// ws layout (bytes, all 16-aligned)
#define WCAT_OFF 0u
#define AB_OFF   1048576u
#define W2TH_OFF 205848576u
#define W2TL_OFF 206110720u
#define HIST_OFF 206372864u
#define RS_OFF   206572864u
#define CUR_OFF  206772880u
#define SROW_OFF 206972880u
#define SCOL_OFF 210172880u

__device__ __forceinline__ unsigned short f2bf(float f) {
    unsigned u = __builtin_bit_cast(unsigned, f);
    unsigned r = (u + 0x7fffu + ((u >> 16) & 1u)) >> 16;
    return (unsigned short)r;
}
__device__ __forceinline__ float bf2f(unsigned short h) {
    unsigned u = ((unsigned)h) << 16;
    return __builtin_bit_cast(float, u);
}

// ---------------- Wcat prep ----------------
__global__ void build_wcat(const float* __restrict__ W1, float* __restrict__ Wcat) {
    int idx = blockIdx.x * 256 + threadIdx.x;   // 262144
    int k = idx >> 10;
    int c = idx & 1023;
    float v;
    if (c < 512) v = W1[k * 512 + c] - W1[(k + 256) * 512 + c];
    else         v = W1[(k + 256) * 512 + (c - 512)];
    Wcat[idx] = v;
}

// ---------------- W2 transpose + bf16 hi/lo split: w2t*[col][k] ----------------
__global__ void build_w2t(const float* __restrict__ W2,
                          unsigned short* __restrict__ w2th,
                          unsigned short* __restrict__ w2tl) {
    int idx = blockIdx.x * 256 + threadIdx.x;   // 131072
    int k = idx >> 8;      // 0..511
    int c = idx & 255;
    float v = W2[idx];
    unsigned short hi = f2bf(v);
    unsigned short lo = f2bf(v - bf2f(hi));
    w2th[c * 512 + k] = hi;
    w2tl[c * 512 + k] = lo;
}

// ---------------- zero helpers ----------------
__global__ void zero_out(float4* __restrict__ out) {
    out[(size_t)blockIdx.x * 256 + threadIdx.x] = float4{0.f, 0.f, 0.f, 0.f};
}
__global__ void zero_ints(int* __restrict__ p, int n) {
    int i = blockIdx.x * 256 + threadIdx.x;
    if (i < n) p[i] = 0;
}

// ---------------- edge sort: histogram -> scan -> scatter ----------------
__global__ void hist_rows(const int* __restrict__ eidx, int* __restrict__ hist) {
    int e = blockIdx.x * 256 + threadIdx.x;
    if (e < N_EDGES) atomicAdd(&hist[eidx[e]], 1);
}

__global__ void scan50k(const int* __restrict__ hist, int* __restrict__ rowStart,
                        int* __restrict__ cursor) {
    __shared__ int part[1024];
    int t = threadIdx.x;
    int base = t * 49;
    int sum = 0;
    for (int i = 0; i < 49; ++i) {
        int idx = base + i;
        if (idx < N_NODES) sum += hist[idx];
    }
    part[t] = sum;
    __syncthreads();
    for (int off = 1; off < 1024; off <<= 1) {
        int v = (t >= off) ? part[t - off] : 0;
        __syncthreads();
        part[t] += v;
        __syncthreads();
    }
    int run = part[t] - sum;   // exclusive prefix
    for (int i = 0; i < 49; ++i) {
        int idx = base + i;
        if (idx < N_NODES) {
            rowStart[idx] = run;
            cursor[idx]   = run;
            run += hist[idx];
        }
    }
    if (t == 1023) rowStart[N_NODES] = run;
}

__global__ void scatter_edges(const int* __restrict__ eidx, int* __restrict__ cursor,
                              int* __restrict__ srow, int* __restrict__ scol) {
    int e = blockIdx.x * 256 + threadIdx.x;
    if (e >= N_EDGES) return;
    int r = eidx[e];
    int p = atomicAdd(&cursor[r], 1);
    srow[p] = r;
    scol[p] = eidx[N_EDGES + e];
}

// ---------------- node GEMM: AB[N,1024] = x[N,256] @ Wcat[256,1024] (+b1 on cols<512) ----
__launch_bounds__(256, 2)
__global__ void node_gemm(const float* __restrict__ x, const float* __restrict__ Wcat,
                          const float* __restrict__ b1, float* __restrict__ AB) {
    __shared__ float xT[32][128];
    __shared__ float wT[32][128];
    const int t  = threadIdx.x;
    const int m0 = blockIdx.x * 128;
    const int c0 = blockIdx.y * 128;
    const int er = t >> 4, ec = t & 15;

    float acc[8][8];
    #pragma unroll
    for (int i = 0; i < 8; ++i)
        #pragma unroll
        for (int j = 0; j < 8; ++j) acc[i][j] = 0.f;

    for (int k0 = 0; k0 < 256; k0 += 32) {
        {
            int mr = t & 127, half = t >> 7;
            int row = m0 + mr; if (row >= N_NODES) row = N_NODES - 1;
            const float* src = x + (size_t)row * 256 + k0 + half * 16;
            #pragma unroll
            for (int j = 0; j < 4; ++j) {
                float4 v = *(const float4*)(src + 4 * j);
                int kk = half * 16 + 4 * j;
                xT[kk + 0][mr] = v.x; xT[kk + 1][mr] = v.y;
                xT[kk + 2][mr] = v.z; xT[kk + 3][mr] = v.w;
            }
        }
        {
            int kk = t >> 5, cc = (t & 31) * 4;
            #pragma unroll
            for (int r = 0; r < 4; ++r) {
                float4 v = *(const float4*)(Wcat + (size_t)(k0 + kk + 8 * r) * 1024 + c0 + cc);
                *(float4*)&wT[kk + 8 * r][cc] = v;
            }
        }
        __syncthreads();
        #pragma unroll 4
        for (int kk = 0; kk < 32; ++kk) {
            float a[8], b[8];
            *(float4*)&a[0] = *(const float4*)&xT[kk][er * 8];
            *(float4*)&a[4] = *(const float4*)&xT[kk][er * 8 + 4];
            *(float4*)&b[0] = *(const float4*)&wT[kk][ec * 8];
            *(float4*)&b[4] = *(const float4*)&wT[kk][ec * 8 + 4];
            #pragma unroll
            for (int i = 0; i < 8; ++i)
                #pragma unroll
                for (int j = 0; j < 8; ++j) acc[i][j] += a[i] * b[j];
        }
        __syncthreads();
    }
    float bias[8];
    if (c0 < 512) {
        *(float4*)&bias[0] = *(const float4*)(b1 + c0 + ec * 8);
        *(float4*)&bias[4] = *(const float4*)(b1 + c0 + ec * 8 + 4);
    } else {
        #pragma unroll
        for (int j = 0; j < 8; ++j) bias[j] = 0.f;
    }
    #pragma unroll
    for (int i = 0; i < 8; ++i) {
        int row = m0 + er * 8 + i;
        if (row < N_NODES) {
            float o[8];
            #pragma unroll
            for (int j = 0; j < 8; ++j) o[j] = acc[i][j] + bias[j];
            float* dst = AB + (size_t)row * 1024 + c0 + ec * 8;
            *(float4*)(dst)     = *(float4*)&o[0];
            *(float4*)(dst + 4) = *(float4*)&o[4];
        }
    }
}

// ---------------- edge GEMM (MFMA): 64 sorted edges x 256 cols per block ----------------
// 4 waves, wave w covers cols [w*64, w*64+64), ALL 64 edges (i = 4 edge-groups of 16).
// K = 512 in 16 steps of 32. 2-product: bf16(h)@W2hi + bf16(h)@W2lo.
// LDS h tile: [64 edges][40] ushort (32 k + 8 pad), double-buffered = 10.25 KB.
__launch_bounds__(256, 4)
__global__ void edge_gemm_mfma(const float* __restrict__ AB,
                               const unsigned short* __restrict__ w2th,
                               const unsigned short* __restrict__ w2tl,
                               const float* __restrict__ b2,
                               const int* __restrict__ srow,
                               const int* __restrict__ scol,
                               float* __restrict__ out) {
    __shared__ unsigned short hHi[2][64][40];    // 10.25 KB
    __shared__ int rowS[64];

    const int t   = threadIdx.x;
    const int l   = t & 63;
    const int w   = t >> 6;
    const int wc0 = w * 64;
    const int e0  = blockIdx.x * 64;
    const int el  = t >> 2;           // staging edge 0..63
    const int q   = t & 3;            // staging k-quarter (8 floats)

    if (t < 64) rowS[t] = srow[e0 + t];
    const int rA = srow[e0 + el];
    const int cA = scol[e0 + el];
    const float* rowPtr = AB + (size_t)rA * 1024;
    const float* colPtr = AB + (size_t)cA * 1024 + 512;

    f32x4 acc[4][4];
    #pragma unroll
    for (int i = 0; i < 4; ++i)
        #pragma unroll
        for (int j = 0; j < 4; ++j) acc[i][j] = f32x4{0.f, 0.f, 0.f, 0.f};

    // ---- prologue: stage step 0 into buffer 0 ----
    {
        float4 a0 = *(const float4*)(rowPtr + q * 8);
        float4 a1 = *(const float4*)(rowPtr + q * 8 + 4);
        float4 b0 = *(const float4*)(colPtr + q * 8);
        float4 b1 = *(const float4*)(colPtr + q * 8 + 4);
        unsigned short hs[8];
        hs[0] = f2bf(fmaxf(a0.x + b0.x, 0.f));
        hs[1] = f2bf(fmaxf(a0.y + b0.y, 0.f));
        hs[2] = f2bf(fmaxf(a0.z + b0.z, 0.f));
        hs[3] = f2bf(fmaxf(a0.w + b0.w, 0.f));
        hs[4] = f2bf(fmaxf(a1.x + b1.x, 0.f));
        hs[5] = f2bf(fmaxf(a1.y + b1.y, 0.f));
        hs[6] = f2bf(fmaxf(a1.z + b1.z, 0.f));
        hs[7] = f2bf(fmaxf(a1.w + b1.w, 0.f));
        *(ushort8*)(&hHi[0][el][q * 8]) = *(ushort8*)&hs[0];
    }
    __syncthreads();

    const int boff = (wc0 + (l & 15)) * 512 + (l >> 4) * 8; // ushort index into w2t
    const int arow = l & 15;                                 // edge within 16-group
    const int aslot = (l >> 4) * 8;                          // k-slot offset

    for (int step = 0; step < 16; ++step) {
        const int cur = step & 1;
        // 1. issue gathers for next step
        float4 nA0, nA1, nB0, nB1;
        if (step < 15) {
            const int k0n = (step + 1) * 32 + q * 8;
            nA0 = *(const float4*)(rowPtr + k0n);
            nA1 = *(const float4*)(rowPtr + k0n + 4);
            nB0 = *(const float4*)(colPtr + k0n);
            nB1 = *(const float4*)(colPtr + k0n + 4);
        }
        // 2. A fragments from LDS (once per step)
        bf16x8 ah[4];
        #pragma unroll
        for (int i = 0; i < 4; ++i)
            ah[i] = *(const bf16x8*)(&hHi[cur][i * 16 + arow][aslot]);
        // 3. j-loop: load W2 fragments (L2-resident), 2-product MFMA
        const int k0 = step * 32;
        #pragma unroll
        for (int j = 0; j < 4; ++j) {
            bf16x8 bh = *(const bf16x8*)(w2th + boff + j * 16 * 512 + k0);
            bf16x8 bl = *(const bf16x8*)(w2tl + boff + j * 16 * 512 + k0);
            #pragma unroll
            for (int i = 0; i < 4; ++i) {
                acc[i][j] = __builtin_amdgcn_mfma_f32_16x16x32_bf16(ah[i], bh, acc[i][j], 0, 0, 0);
                acc[i][j] = __builtin_amdgcn_mfma_f32_16x16x32_bf16(ah[i], bl, acc[i][j], 0, 0, 0);
            }
        }
        // 4. compute h(next), write other buffer
        if (step < 15) {
            unsigned short hs[8];
            hs[0] = f2bf(fmaxf(nA0.x + nB0.x, 0.f));
            hs[1] = f2bf(fmaxf(nA0.y + nB0.y, 0.f));
            hs[2] = f2bf(fmaxf(nA0.z + nB0.z, 0.f));
            hs[3] = f2bf(fmaxf(nA0.w + nB0.w, 0.f));
            hs[4] = f2bf(fmaxf(nA1.x + nB1.x, 0.f));
            hs[5] = f2bf(fmaxf(nA1.y + nB1.y, 0.f));
            hs[6] = f2bf(fmaxf(nA1.z + nB1.z, 0.f));
            hs[7] = f2bf(fmaxf(nA1.w + nB1.w, 0.f));
            *(ushort8*)(&hHi[cur ^ 1][el][q * 8]) = *(ushort8*)&hs[0];
        }
        __syncthreads();
    }

    // ---- epilogue: + b2, quad-collapse same-row atomics ----
    float bv[4];
    #pragma unroll
    for (int j = 0; j < 4; ++j) bv[j] = b2[wc0 + j * 16 + (l & 15)];
    const int eg = (l >> 4) * 4;
    #pragma unroll
    for (int i = 0; i < 4; ++i) {
        const int eb = i * 16 + eg;
        const int r0 = rowS[eb], r1 = rowS[eb + 1], r2 = rowS[eb + 2], r3 = rowS[eb + 3];
        const bool same = (r0 == r1) & (r1 == r2) & (r2 == r3);
        #pragma unroll
        for (int j = 0; j < 4; ++j) {
            const int col = wc0 + j * 16 + (l & 15);
            f32x4 a = acc[i][j];
            if (same) {
                unsafeAtomicAdd(out + (size_t)r0 * 256 + col,
                                a[0] + a[1] + a[2] + a[3] + 4.f * bv[j]);
            } else {
                unsafeAtomicAdd(out + (size_t)r0 * 256 + col, a[0] + bv[j]);
                unsafeAtomicAdd(out + (size_t)r1 * 256 + col, a[1] + bv[j]);
                unsafeAtomicAdd(out + (size_t)r2 * 256 + col, a[2] + bv[j]);
                unsafeAtomicAdd(out + (size_t)r3 * 256 + col, a[3] + bv[j]);
            }
        }
    }
}

extern "C" void kernel_launch(void* const* d_in, const int* in_sizes, int n_in,
                              void* d_out, int out_size, void* d_ws, size_t ws_size,
                              hipStream_t stream) {
    const float* x   = (const float*)d_in[0];
    const int*   eix = (const int*)d_in[1];
    const float* W1  = (const float*)d_in[2];
    const float* b1  = (const float*)d_in[3];
    const float* W2  = (const float*)d_in[4];
    const float* b2  = (const float*)d_in[5];
    float* out = (float*)d_out;
    char*  ws  = (char*)d_ws;

    float*          Wcat   = (float*)(ws + WCAT_OFF);
    float*          AB     = (float*)(ws + AB_OFF);
    unsigned short* w2th   = (unsigned short*)(ws + W2TH_OFF);
    unsigned short* w2tl   = (unsigned short*)(ws + W2TL_OFF);
    int*            hist   = (int*)(ws + HIST_OFF);
    int*            rowSt  = (int*)(ws + RS_OFF);
    int*            cursor = (int*)(ws + CUR_OFF);
    int*            srow   = (int*)(ws + SROW_OFF);
    int*            scol   = (int*)(ws + SCOL_OFF);

    build_wcat<<<1024, 256, 0, stream>>>(W1, Wcat);
    build_w2t<<<512, 256, 0, stream>>>(W2, w2th, w2tl);
    zero_ints<<<196, 256, 0, stream>>>(hist, N_NODES);
    zero_out<<<12500, 256, 0, stream>>>((float4*)out);
    node_gemm<<<dim3(391, 8), 256, 0, stream>>>(x, Wcat, b1, AB);
    hist_rows<<<3125, 256, 0, stream>>>(eix, hist);
    scan50k<<<1, 1024, 0, stream>>>(hist, rowSt, cursor);
    scatter_edges<<<3125, 256, 0, stream>>>(eix, cursor, srow, scol);
    edge_gemm_mfma<<<12500, 256, 0, stream>>>(AB, w2th, w2tl, b2, srow, scol, out);
}

// Round 12
// 1569.693 us; speedup vs baseline: 1.1733x; 1.1733x over previous
//
#include <hip/hip_runtime.h>

// EdgeConv: sorted edges + MFMA bf16-split edge GEMM (round-8 structure).
// Round-12 change: K-loop VMEM issue order — W2 (L2) loads issued BEFORE the
// next-step AB gathers (L3). vmcnt is an ordered counter: with gathers issued
// first, waiting for W2 values forces vmcnt(0) and serializes the L3 gather
// latency ahead of every MFMA cluster. Issuing W2 first lets MFMAs start after
// only the W2 wait, with gathers completing in the background.

#define N_NODES 50000
#define N_EDGES 800000

typedef __attribute__((ext_vector_type(8))) short  bf16x8;
typedef __attribute__((ext_vector_type(8))) unsigned short ushort8;
typedef __attribute__((ext_vector_type(4))) float  f32x4;

// ws layout (bytes, all 16-aligned)
#define WCAT_OFF 0u
#define AB_OFF   1048576u
#define W2TH_OFF 205848576u
#define W2TL_OFF 206110720u
#define HIST_OFF 206372864u
#define RS_OFF   206572864u
#define CUR_OFF  206772880u
#define SROW_OFF 206972880u
#define SCOL_OFF 210172880u

__device__ __forceinline__ unsigned short f2bf(float f) {
    unsigned u = __builtin_bit_cast(unsigned, f);
    unsigned r = (u + 0x7fffu + ((u >> 16) & 1u)) >> 16;
    return (unsigned short)r;
}
__device__ __forceinline__ float bf2f(unsigned short h) {
    unsigned u = ((unsigned)h) << 16;
    return __builtin_bit_cast(float, u);
}

// ---------------- Wcat prep ----------------
__global__ void build_wcat(const float* __restrict__ W1, float* __restrict__ Wcat) {
    int idx = blockIdx.x * 256 + threadIdx.x;   // 262144
    int k = idx >> 10;
    int c = idx & 1023;
    float v;
    if (c < 512) v = W1[k * 512 + c] - W1[(k + 256) * 512 + c];
    else         v = W1[(k + 256) * 512 + (c - 512)];
    Wcat[idx] = v;
}

// ---------------- W2 transpose + bf16 hi/lo split: w2t*[col][k] ----------------
__global__ void build_w2t(const float* __restrict__ W2,
                          unsigned short* __restrict__ w2th,
                          unsigned short* __restrict__ w2tl) {
    int idx = blockIdx.x * 256 + threadIdx.x;   // 131072
    int k = idx >> 8;      // 0..511
    int c = idx & 255;
    float v = W2[idx];
    unsigned short hi = f2bf(v);
    unsigned short lo = f2bf(v - bf2f(hi));
    w2th[c * 512 + k] = hi;
    w2tl[c * 512 + k] = lo;
}

// ---------------- zero helpers ----------------
__global__ void zero_out(float4* __restrict__ out) {
    out[(size_t)blockIdx.x * 256 + threadIdx.x] = float4{0.f, 0.f, 0.f, 0.f};
}
__global__ void zero_ints(int* __restrict__ p, int n) {
    int i = blockIdx.x * 256 + threadIdx.x;
    if (i < n) p[i] = 0;
}

// ---------------- edge sort: histogram -> scan -> scatter ----------------
__global__ void hist_rows(const int* __restrict__ eidx, int* __restrict__ hist) {
    int e = blockIdx.x * 256 + threadIdx.x;
    if (e < N_EDGES) atomicAdd(&hist[eidx[e]], 1);
}

__global__ void scan50k(const int* __restrict__ hist, int* __restrict__ rowStart,
                        int* __restrict__ cursor) {
    __shared__ int part[1024];
    int t = threadIdx.x;
    int base = t * 49;
    int sum = 0;
    for (int i = 0; i < 49; ++i) {
        int idx = base + i;
        if (idx < N_NODES) sum += hist[idx];
    }
    part[t] = sum;
    __syncthreads();
    for (int off = 1; off < 1024; off <<= 1) {
        int v = (t >= off) ? part[t - off] : 0;
        __syncthreads();
        part[t] += v;
        __syncthreads();
    }
    int run = part[t] - sum;   // exclusive prefix
    for (int i = 0; i < 49; ++i) {
        int idx = base + i;
        if (idx < N_NODES) {
            rowStart[idx] = run;
            cursor[idx]   = run;
            run += hist[idx];
        }
    }
    if (t == 1023) rowStart[N_NODES] = run;
}

__global__ void scatter_edges(const int* __restrict__ eidx, int* __restrict__ cursor,
                              int* __restrict__ srow, int* __restrict__ scol) {
    int e = blockIdx.x * 256 + threadIdx.x;
    if (e >= N_EDGES) return;
    int r = eidx[e];
    int p = atomicAdd(&cursor[r], 1);
    srow[p] = r;
    scol[p] = eidx[N_EDGES + e];
}

// ---------------- node GEMM: AB[N,1024] = x[N,256] @ Wcat[256,1024] (+b1 on cols<512) ----
__launch_bounds__(256, 2)
__global__ void node_gemm(const float* __restrict__ x, const float* __restrict__ Wcat,
                          const float* __restrict__ b1, float* __restrict__ AB) {
    __shared__ float xT[32][128];
    __shared__ float wT[32][128];
    const int t  = threadIdx.x;
    const int m0 = blockIdx.x * 128;
    const int c0 = blockIdx.y * 128;
    const int er = t >> 4, ec = t & 15;

    float acc[8][8];
    #pragma unroll
    for (int i = 0; i < 8; ++i)
        #pragma unroll
        for (int j = 0; j < 8; ++j) acc[i][j] = 0.f;

    for (int k0 = 0; k0 < 256; k0 += 32) {
        {
            int mr = t & 127, half = t >> 7;
            int row = m0 + mr; if (row >= N_NODES) row = N_NODES - 1;
            const float* src = x + (size_t)row * 256 + k0 + half * 16;
            #pragma unroll
            for (int j = 0; j < 4; ++j) {
                float4 v = *(const float4*)(src + 4 * j);
                int kk = half * 16 + 4 * j;
                xT[kk + 0][mr] = v.x; xT[kk + 1][mr] = v.y;
                xT[kk + 2][mr] = v.z; xT[kk + 3][mr] = v.w;
            }
        }
        {
            int kk = t >> 5, cc = (t & 31) * 4;
            #pragma unroll
            for (int r = 0; r < 4; ++r) {
                float4 v = *(const float4*)(Wcat + (size_t)(k0 + kk + 8 * r) * 1024 + c0 + cc);
                *(float4*)&wT[kk + 8 * r][cc] = v;
            }
        }
        __syncthreads();
        #pragma unroll 4
        for (int kk = 0; kk < 32; ++kk) {
            float a[8], b[8];
            *(float4*)&a[0] = *(const float4*)&xT[kk][er * 8];
            *(float4*)&a[4] = *(const float4*)&xT[kk][er * 8 + 4];
            *(float4*)&b[0] = *(const float4*)&wT[kk][ec * 8];
            *(float4*)&b[4] = *(const float4*)&wT[kk][ec * 8 + 4];
            #pragma unroll
            for (int i = 0; i < 8; ++i)
                #pragma unroll
                for (int j = 0; j < 8; ++j) acc[i][j] += a[i] * b[j];
        }
        __syncthreads();
    }
    float bias[8];
    if (c0 < 512) {
        *(float4*)&bias[0] = *(const float4*)(b1 + c0 + ec * 8);
        *(float4*)&bias[4] = *(const float4*)(b1 + c0 + ec * 8 + 4);
    } else {
        #pragma unroll
        for (int j = 0; j < 8; ++j) bias[j] = 0.f;
    }
    #pragma unroll
    for (int i = 0; i < 8; ++i) {
        int row = m0 + er * 8 + i;
        if (row < N_NODES) {
            float o[8];
            #pragma unroll
            for (int j = 0; j < 8; ++j) o[j] = acc[i][j] + bias[j];
            float* dst = AB + (size_t)row * 1024 + c0 + ec * 8;
            *(float4*)(dst)     = *(float4*)&o[0];
            *(float4*)(dst + 4) = *(float4*)&o[4];
        }
    }
}

// ---------------- edge GEMM (MFMA): 128 sorted edges x 256 cols per block ----------------
// 4 waves, wave w covers cols [w*64, w*64+64). K = 512 in 16 steps of 32.
// LDS h tiles: [128 edges][40] ushort (32 k + 8 pad -> stride 20 dwords, uniform banks).
// VMEM issue order per step: W2 (L2) first, next-step gathers (L3) LAST.
__launch_bounds__(256, 2)
__global__ void edge_gemm_mfma(const float* __restrict__ AB,
                               const unsigned short* __restrict__ w2th,
                               const unsigned short* __restrict__ w2tl,
                               const float* __restrict__ b2,
                               const int* __restrict__ srow,
                               const int* __restrict__ scol,
                               float* __restrict__ out) {
    __shared__ unsigned short hHi[2][128][40];   // 20 KB
    __shared__ unsigned short hLo[2][128][40];   // 20 KB
    __shared__ int rowS[128];

    const int t   = threadIdx.x;
    const int l   = t & 63;
    const int w   = t >> 6;
    const int wc0 = w * 64;
    const int e0  = blockIdx.x * 128;
    const int el  = t & 127;          // staging edge
    const int half = t >> 7;          // staging k-half (0/1)

    if (t < 128) rowS[t] = srow[e0 + t];
    const int rA = srow[e0 + el];
    const int cA = scol[e0 + el];
    const float* rowPtr = AB + (size_t)rA * 1024;
    const float* colPtr = AB + (size_t)cA * 1024 + 512;

    f32x4 acc[8][4];
    #pragma unroll
    for (int i = 0; i < 8; ++i)
        #pragma unroll
        for (int j = 0; j < 4; ++j) acc[i][j] = f32x4{0.f, 0.f, 0.f, 0.f};

    // ---- prologue: stage step 0 into buffer 0 ----
    {
        float hv[16];
        #pragma unroll
        for (int q = 0; q < 4; ++q) {
            float4 va = *(const float4*)(rowPtr + half * 16 + 4 * q);
            float4 vb = *(const float4*)(colPtr + half * 16 + 4 * q);
            hv[4 * q + 0] = fmaxf(va.x + vb.x, 0.f);
            hv[4 * q + 1] = fmaxf(va.y + vb.y, 0.f);
            hv[4 * q + 2] = fmaxf(va.z + vb.z, 0.f);
            hv[4 * q + 3] = fmaxf(va.w + vb.w, 0.f);
        }
        unsigned short hs[16], ls[16];
        #pragma unroll
        for (int m = 0; m < 16; ++m) {
            hs[m] = f2bf(hv[m]);
            ls[m] = f2bf(hv[m] - bf2f(hs[m]));
        }
        #pragma unroll
        for (int s = 0; s < 2; ++s) {
            *(ushort8*)(&hHi[0][el][(half * 2 + s) * 8]) = *(ushort8*)&hs[8 * s];
            *(ushort8*)(&hLo[0][el][(half * 2 + s) * 8]) = *(ushort8*)&ls[8 * s];
        }
    }
    __syncthreads();

    const int aoff = (l & 15) * 40 + (l >> 4) * 8;          // ushort index into h tile
    const int boff = (wc0 + (l & 15)) * 512 + (l >> 4) * 8; // base ushort index into w2t

    for (int step = 0; step < 16; ++step) {
        const int cur = step & 1;
        const int k0 = step * 32;
        // 1. W2 B fragments for current step — ISSUE FIRST (L2-resident, short wait)
        bf16x8 bh[4], bl[4];
        #pragma unroll
        for (int j = 0; j < 4; ++j) {
            bh[j] = *(const bf16x8*)(w2th + boff + j * 16 * 512 + k0);
            bl[j] = *(const bf16x8*)(w2tl + boff + j * 16 * 512 + k0);
        }
        // 2. next-step gathers — ISSUE LAST (L3 latency hides under MFMA below;
        //    MFMA's W2 wait leaves these outstanding since they are newest)
        float4 nA[4], nB[4];
        if (step < 15) {
            const int k0n = (step + 1) * 32 + half * 16;
            #pragma unroll
            for (int q = 0; q < 4; ++q) {
                nA[q] = *(const float4*)(rowPtr + k0n + 4 * q);
                nB[q] = *(const float4*)(colPtr + k0n + 4 * q);
            }
        }
        // 3. A fragments from LDS + MFMA (3-product bf16 split)
        const unsigned short* hbH = &hHi[cur][0][0];
        const unsigned short* hbL = &hLo[cur][0][0];
        #pragma unroll
        for (int i = 0; i < 8; ++i) {
            bf16x8 ah = *(const bf16x8*)(hbH + i * 640 + aoff);
            bf16x8 al = *(const bf16x8*)(hbL + i * 640 + aoff);
            #pragma unroll
            for (int j = 0; j < 4; ++j) {
                acc[i][j] = __builtin_amdgcn_mfma_f32_16x16x32_bf16(ah, bh[j], acc[i][j], 0, 0, 0);
                acc[i][j] = __builtin_amdgcn_mfma_f32_16x16x32_bf16(al, bh[j], acc[i][j], 0, 0, 0);
                acc[i][j] = __builtin_amdgcn_mfma_f32_16x16x32_bf16(ah, bl[j], acc[i][j], 0, 0, 0);
            }
        }
        // 4. compute h(next) (waits the gathers), write other buffer
        if (step < 15) {
            float hv[16];
            #pragma unroll
            for (int q = 0; q < 4; ++q) {
                hv[4 * q + 0] = fmaxf(nA[q].x + nB[q].x, 0.f);
                hv[4 * q + 1] = fmaxf(nA[q].y + nB[q].y, 0.f);
                hv[4 * q + 2] = fmaxf(nA[q].z + nB[q].z, 0.f);
                hv[4 * q + 3] = fmaxf(nA[q].w + nB[q].w, 0.f);
            }
            unsigned short hs[16], ls[16];
            #pragma unroll
            for (int m = 0; m < 16; ++m) {
                hs[m] = f2bf(hv[m]);
                ls[m] = f2bf(hv[m] - bf2f(hs[m]));
            }
            const int nxt = cur ^ 1;
            #pragma unroll
            for (int s = 0; s < 2; ++s) {
                *(ushort8*)(&hHi[nxt][el][(half * 2 + s) * 8]) = *(ushort8*)&hs[8 * s];
                *(ushort8*)(&hLo[nxt][el][(half * 2 + s) * 8]) = *(ushort8*)&ls[8 * s];
            }
        }
        __syncthreads();
    }

    // ---- epilogue: + b2, quad-collapse same-row atomics ----
    float bv[4];
    #pragma unroll
    for (int j = 0; j < 4; ++j) bv[j] = b2[wc0 + j * 16 + (l & 15)];
    const int eg = (l >> 4) * 4;
    #pragma unroll
    for (int i = 0; i < 8; ++i) {
        const int eb = i * 16 + eg;
        const int r0 = rowS[eb], r1 = rowS[eb + 1], r2 = rowS[eb + 2], r3 = rowS[eb + 3];
        const bool same = (r0 == r1) & (r1 == r2) & (r2 == r3);
        #pragma unroll
        for (int j = 0; j < 4; ++j) {
            const int col = wc0 + j * 16 + (l & 15);
            f32x4 a = acc[i][j];
            if (same) {
                unsafeAtomicAdd(out + (size_t)r0 * 256 + col,
                                a[0] + a[1] + a[2] + a[3] + 4.f * bv[j]);
            } else {
                unsafeAtomicAdd(out + (size_t)r0 * 256 + col, a[0] + bv[j]);
                unsafeAtomicAdd(out + (size_t)r1 * 256 + col, a[1] + bv[j]);
                unsafeAtomicAdd(out + (size_t)r2 * 256 + col, a[2] + bv[j]);
                unsafeAtomicAdd(out + (size_t)r3 * 256 + col, a[3] + bv[j]);
            }
        }
    }
}

extern "C" void kernel_launch(void* const* d_in, const int* in_sizes, int n_in,
                              void* d_out, int out_size, void* d_ws, size_t ws_size,
                              hipStream_t stream) {
    const float* x   = (const float*)d_in[0];
    const int*   eix = (const int*)d_in[1];
    const float* W1  = (const float*)d_in[2];
    const float* b1  = (const float*)d_in[3];
    const float* W2  = (const float*)d_in[4];
    const float* b2  = (const float*)d_in[5];
    float* out = (float*)d_out;
    char*  ws  = (char*)d_ws;

    float*          Wcat   = (float*)(ws + WCAT_OFF);
    float*          AB     = (float*)(ws + AB_OFF);
    unsigned short* w2th   = (unsigned short*)(ws + W2TH_OFF);
    unsigned short* w2tl   = (unsigned short*)(ws + W2TL_OFF);
    int*            hist   = (int*)(ws + HIST_OFF);
    int*            rowSt  = (int*)(ws + RS_OFF);
    int*            cursor = (int*)(ws + CUR_OFF);
    int*            srow   = (int*)(ws + SROW_OFF);
    int*            scol   = (int*)(ws + SCOL_OFF);

    build_wcat<<<1024, 256, 0, stream>>>(W1, Wcat);
    build_w2t<<<512, 256, 0, stream>>>(W2, w2th, w2tl);
    zero_ints<<<196, 256, 0, stream>>>(hist, N_NODES);
    zero_out<<<12500, 256, 0, stream>>>((float4*)out);
    node_gemm<<<dim3(391, 8), 256, 0, stream>>>(x, Wcat, b1, AB);
    hist_rows<<<3125, 256, 0, stream>>>(eix, hist);
    scan50k<<<1, 1024, 0, stream>>>(hist, rowSt, cursor);
    scatter_edges<<<3125, 256, 0, stream>>>(eix, cursor, srow, scol);
    edge_gemm_mfma<<<6250, 256, 0, stream>>>(AB, w2th, w2tl, b2, srow, scol, out);
}